// Round 3
// baseline (38.163 us; speedup 1.0000x reference)
//
#include <hip/hip_runtime.h>
#include <math.h>

// inputs [B=1024, 7, 7, C=512] f32 NHWC; out [B, 512]:
//   out[b][0:22]          = top-22 of center pixel (3,3)  (k_c = 512%49)
//   out[b][22 + p*10 + j] = top-10 of pixel p             (k_pp = 512//49)
#define NPIX 49
#define C_CH 512
#define CENTER_PIX 24
#define K_PP 10
#define K_C 22
#define WAVES_PER_BLOCK 4

#define CE(i, j)                       \
    do {                               \
        float _a = v[i], _b = v[j];    \
        v[i] = fmaxf(_a, _b);          \
        v[j] = fminf(_a, _b);          \
    } while (0)

// Sort 8 elements descending — Batcher odd-even mergesort, 19 comparators.
__device__ __forceinline__ void sort8_desc(float (&v)[8]) {
    CE(0, 1); CE(2, 3); CE(4, 5); CE(6, 7);
    CE(0, 2); CE(1, 3); CE(4, 6); CE(5, 7);
    CE(1, 2); CE(5, 6);
    CE(0, 4); CE(1, 5); CE(2, 6); CE(3, 7);
    CE(2, 4); CE(3, 5);
    CE(1, 2); CE(3, 4); CE(5, 6);
}

// x = max(x, dpp_perm(x)); VALU-only. old = self -> invalid lanes harmless.
template <int CTRL>
__device__ __forceinline__ float dpp_maxf(float x) {
    int xi = __float_as_int(x);
    int yi = __builtin_amdgcn_update_dpp(xi, xi, CTRL, 0xF, 0xF, false);
    return fmaxf(x, __int_as_float(yi));
}

// xor-16 butterfly max via gfx950 v_permlane16_swap_b32. With both operands
// = x, the two outputs at lane i are {x[i], x[i^16]} in some order, so the
// max is direction-agnostic.
__device__ __forceinline__ float swap16_maxf(float x) {
    const int xi = __float_as_int(x);
    auto r = __builtin_amdgcn_permlane16_swap(xi, xi, false, false);
    return fmaxf(__int_as_float((int)r[0]), __int_as_float((int)r[1]));
}

// xor-32 butterfly max via v_permlane32_swap_b32.
__device__ __forceinline__ float swap32_maxf(float x) {
    const int xi = __float_as_int(x);
    auto r = __builtin_amdgcn_permlane32_swap(xi, xi, false, false);
    return fmaxf(__int_as_float((int)r[0]), __int_as_float((int)r[1]));
}

// Full 64-lane max, result uniform across the wave IN A VGPR (no readlane,
// no SGPR round-trip): rotate-reduce within 16-lane rows, then 16/32 swaps.
__device__ __forceinline__ float wave_allmax(float x) {
    x = dpp_maxf<0x121>(x);  // row_ror:1
    x = dpp_maxf<0x122>(x);  // row_ror:2
    x = dpp_maxf<0x124>(x);  // row_ror:4
    x = dpp_maxf<0x128>(x);  // row_ror:8 -> every lane has its row's max
    x = swap16_maxf(x);      // xor 16
    x = swap32_maxf(x);      // xor 32
    return x;
}

// One extraction round on one pixel's state. Lowest lane among ties owns the
// max and shifts its sorted list down (static indexing -> stays in VGPRs).
// Lane `it` records the round's max into res.
__device__ __forceinline__ void round1(float (&v)[8], float& res, int lane, int it) {
    const float m = wave_allmax(v[0]);
    const unsigned long long msk = __ballot(v[0] == m);
    const int owner = __ffsll((unsigned long long)msk) - 1;
    const bool own = (lane == owner);
    v[0] = own ? v[1] : v[0];
    v[1] = own ? v[2] : v[1];
    v[2] = own ? v[3] : v[2];
    v[3] = own ? v[4] : v[3];
    v[4] = own ? v[5] : v[4];
    v[5] = own ? v[6] : v[5];
    v[6] = own ? v[7] : v[6];
    v[7] = own ? -INFINITY : v[7];
    res = (lane == it) ? m : res;
}

__device__ __forceinline__ void store_pixel(float* __restrict__ out, int f,
                                            float res, int lane) {
    const int b = f / NPIX;
    const int p = f - b * NPIX;
    float* ob = out + (size_t)b * C_CH;
    if (p == CENTER_PIX) {
        if (lane < K_C) ob[lane] = res;
        if (lane < K_PP) ob[K_C + CENTER_PIX * K_PP + lane] = res;
    } else {
        if (lane < K_PP) ob[K_C + p * K_PP + lane] = res;
    }
}

__global__ __launch_bounds__(WAVES_PER_BLOCK * 64) void
channel_topk_kernel(const float* __restrict__ in, float* __restrict__ out) {
    const int wave = blockIdx.x * WAVES_PER_BLOCK + (threadIdx.x >> 6);
    const int lane = threadIdx.x & 63;
    const int fA = 2 * wave;      // flat pixel index, pixel A
    const int fB = fA + 1;        // pixel B (contiguous 4 KB with A)

    const float* src = in + (size_t)fA * C_CH;
    const float4 a0 = *reinterpret_cast<const float4*>(src + lane * 4);
    const float4 a1 = *reinterpret_cast<const float4*>(src + 256 + lane * 4);
    const float4 b0 = *reinterpret_cast<const float4*>(src + 512 + lane * 4);
    const float4 b1 = *reinterpret_cast<const float4*>(src + 768 + lane * 4);
    float vA[8] = {a0.x, a0.y, a0.z, a0.w, a1.x, a1.y, a1.z, a1.w};
    float vB[8] = {b0.x, b0.y, b0.z, b0.w, b1.x, b1.y, b1.z, b1.w};

    sort8_desc(vA);
    sort8_desc(vB);

    float resA = 0.0f, resB = 0.0f;
    // Interleave the two independent extraction chains: chain B's ops fill
    // chain A's DPP hazard/latency slots and vice versa.
#pragma unroll
    for (int it = 0; it < K_PP; ++it) {
        round1(vA, resA, lane, it);
        round1(vB, resB, lane, it);
    }
    // Center pixel (4% of waves) continues 12 more rounds; lanes 10..21
    // record into the same res register. Wave-uniform branches.
    if (fA % NPIX == CENTER_PIX) {
#pragma unroll
        for (int it = K_PP; it < K_C; ++it) round1(vA, resA, lane, it);
    }
    if (fB % NPIX == CENTER_PIX) {
#pragma unroll
        for (int it = K_PP; it < K_C; ++it) round1(vB, resB, lane, it);
    }

    store_pixel(out, fA, resA, lane);
    store_pixel(out, fB, resB, lane);
}

extern "C" void kernel_launch(void* const* d_in, const int* in_sizes, int n_in,
                              void* d_out, int out_size, void* d_ws, size_t ws_size,
                              hipStream_t stream) {
    const float* in = (const float*)d_in[0];
    float* out = (float*)d_out;
    const int B = 1024;
    const int total_waves = B * NPIX / 2;                   // 25088
    const int blocks = total_waves / WAVES_PER_BLOCK;       // 6272
    channel_topk_kernel<<<blocks, WAVES_PER_BLOCK * 64, 0, stream>>>(in, out);
}

// Round 4
// 25.430 us; speedup vs baseline: 1.5007x; 1.5007x over previous
//
#include <hip/hip_runtime.h>
#include <math.h>

// inputs [B=1024, 7, 7, C=512] f32 NHWC; out [B, 512]:
//   out[b][0:22]          = top-22 of center pixel (3,3)  (k_c = 512%49)
//   out[b][22 + p*10 + j] = top-10 of pixel p             (k_pp = 512//49)
#define NPIX 49
#define C_CH 512
#define CENTER_PIX 24
#define K_PP 10
#define K_C 22
#define MAIN_BLOCKS 3136    // x4 waves x4 pixels = 50176 pixels
#define CENTER_BLOCKS 256   // x4 waves = 1024 center jobs (one per batch)

__device__ __forceinline__ float ibc(int x) { return __int_as_float(x); }
__device__ __forceinline__ int fbc(float x) { return __float_as_int(x); }

// Descending compare-exchange.
__device__ __forceinline__ void ce(float& a, float& b) {
    const float mx = fmaxf(a, b), mn = fminf(a, b);
    a = mx; b = mn;
}

// Sort 8 descending — Batcher odd-even mergesort, 19 CE. (Proven R1-R3.)
__device__ __forceinline__ void sort8_desc(float* v) {
    ce(v[0],v[1]); ce(v[2],v[3]); ce(v[4],v[5]); ce(v[6],v[7]);
    ce(v[0],v[2]); ce(v[1],v[3]); ce(v[4],v[6]); ce(v[5],v[7]);
    ce(v[1],v[2]); ce(v[5],v[6]);
    ce(v[0],v[4]); ce(v[1],v[5]); ce(v[2],v[6]); ce(v[3],v[7]);
    ce(v[2],v[4]); ce(v[3],v[5]);
    ce(v[1],v[2]); ce(v[3],v[4]); ce(v[5],v[6]);
}

// Clean a cyclic-bitonic 10-seq (the "valley" shape max(desc,asc) produces)
// to descending order. Wiring = padded-16 bitonic cleaner with +inf front
// ghosts removed; hand-verified on valley/monotone cases.
__device__ __forceinline__ void bitonic10_clean(float (&c)[10]) {
    ce(c[0],c[8]); ce(c[1],c[9]);
    ce(c[2],c[6]); ce(c[3],c[7]); ce(c[4],c[8]); ce(c[5],c[9]);
    ce(c[2],c[4]); ce(c[3],c[5]); ce(c[6],c[8]); ce(c[7],c[9]);
    ce(c[0],c[1]); ce(c[2],c[3]); ce(c[4],c[5]); ce(c[6],c[7]); ce(c[8],c[9]);
}

// Merge two descending sorted-8 lists -> descending sorted top-10.
__device__ __forceinline__ void merge88_top10(const float* a, const float* b,
                                              float (&L)[10]) {
    float h[8], l[8];
#pragma unroll
    for (int i = 0; i < 8; ++i) {
        h[i] = fmaxf(a[i], b[7 - i]);   // top-8 (cyclic bitonic)
        l[i] = fminf(a[i], b[7 - i]);   // ranks 9..16 (cyclic bitonic)
    }
    // clean h descending (bitonic-8)
    ce(h[0],h[4]); ce(h[1],h[5]); ce(h[2],h[6]); ce(h[3],h[7]);
    ce(h[0],h[2]); ce(h[1],h[3]); ce(h[4],h[6]); ce(h[5],h[7]);
    ce(h[0],h[1]); ce(h[2],h[3]); ce(h[4],h[5]); ce(h[6],h[7]);
    // sorted top-2 of l
    const float m0 = fmaxf(l[0], l[4]), m1 = fmaxf(l[1], l[5]);
    const float m2 = fmaxf(l[2], l[6]), m3 = fmaxf(l[3], l[7]);
    const float n0 = fmaxf(m0, m2), n1 = fmaxf(m1, m3);
#pragma unroll
    for (int i = 0; i < 8; ++i) L[i] = h[i];
    L[8] = fmaxf(n0, n1);
    L[9] = fminf(n0, n1);
}

// a = top-10 of (a ∪ b); both inputs descending sorted-10.
__device__ __forceinline__ void merge10_into(float (&a)[10], const float (&b)[10]) {
    float c[10];
#pragma unroll
    for (int i = 0; i < 10; ++i) c[i] = fmaxf(a[i], b[9 - i]);
    bitonic10_clean(c);
#pragma unroll
    for (int i = 0; i < 10; ++i) a[i] = c[i];
}

// One cross-lane tree level: merge own T with row-rotated partner's T.
// 10-wide ILP, no serial DPP chain, no ballot.
template <int CTRL>
__device__ __forceinline__ void tree_level(float (&T)[10]) {
    float c[10];
#pragma unroll
    for (int i = 0; i < 10; ++i) {
        const int s = fbc(T[9 - i]);
        const int p = __builtin_amdgcn_update_dpp(s, s, CTRL, 0xF, 0xF, false);
        c[i] = fmaxf(T[i], ibc(p));
    }
    bitonic10_clean(c);
#pragma unroll
    for (int i = 0; i < 10; ++i) T[i] = c[i];
}

// ---- center-pixel path (R2-proven serial extraction, 1024 waves only) ----
template <int CTRL>
__device__ __forceinline__ float dpp_maxf(float x) {
    const int xi = fbc(x);
    const int yi = __builtin_amdgcn_update_dpp(xi, xi, CTRL, 0xF, 0xF, false);
    return fmaxf(x, ibc(yi));
}

__device__ __forceinline__ float wave_max_uniform(float x) {
    x = dpp_maxf<0x111>(x);  // row_shr:1
    x = dpp_maxf<0x112>(x);  // row_shr:2
    x = dpp_maxf<0x114>(x);  // row_shr:4
    x = dpp_maxf<0x118>(x);  // row_shr:8
    x = dpp_maxf<0x142>(x);  // row_bcast15
    x = dpp_maxf<0x143>(x);  // row_bcast31
    return ibc(__builtin_amdgcn_readlane(fbc(x), 63));
}

__device__ __forceinline__ void round1(float (&v)[8], float& res, int lane, int it) {
    const float m = wave_max_uniform(v[0]);
    const unsigned long long msk = __ballot(v[0] == m);
    const int owner = __ffsll(msk) - 1;
    const bool own = (lane == owner);
    v[0] = own ? v[1] : v[0];
    v[1] = own ? v[2] : v[1];
    v[2] = own ? v[3] : v[2];
    v[3] = own ? v[4] : v[3];
    v[4] = own ? v[5] : v[4];
    v[5] = own ? v[6] : v[5];
    v[6] = own ? v[7] : v[6];
    v[7] = own ? -INFINITY : v[7];
    res = (lane == it) ? m : res;
}

__global__ __launch_bounds__(256, 4) void
channel_topk_kernel(const float* __restrict__ in, float* __restrict__ out) {
    const int wid = threadIdx.x >> 6;
    const int lane = threadIdx.x & 63;

    if (blockIdx.x < MAIN_BLOCKS) {
        // ---- main path: 16 lanes per pixel, 4 pixels per wave ----
        const int g = lane & 15;                                  // lane in group
        const int pix = (blockIdx.x * 4 + wid) * 4 + (lane >> 4); // pixel id
        const float* src = in + (size_t)pix * C_CH + g * 4;

        float v[32];
#pragma unroll
        for (int j = 0; j < 8; ++j) {
            const float4 t = *reinterpret_cast<const float4*>(src + j * 64);
            v[j * 4 + 0] = t.x; v[j * 4 + 1] = t.y;
            v[j * 4 + 2] = t.z; v[j * 4 + 3] = t.w;
        }

        sort8_desc(v);          // v[0..7]
        sort8_desc(v + 8);      // v[8..15]
        sort8_desc(v + 16);     // v[16..23]
        sort8_desc(v + 24);     // v[24..31]

        float L1[10], L2[10];
        merge88_top10(v, v + 8, L1);
        merge88_top10(v + 16, v + 24, L2);
        merge10_into(L1, L2);   // L1 = per-lane top-10 of its 32 channels

        // rotate-merge across the 16-lane row: exact binary coverage
        tree_level<0x121>(L1);  // row_ror:1
        tree_level<0x122>(L1);  // row_ror:2
        tree_level<0x124>(L1);  // row_ror:4
        tree_level<0x128>(L1);  // row_ror:8
        // every lane of the row now holds the pixel's sorted top-10

        const int b = pix / NPIX;
        const int p = pix - b * NPIX;
        float r = L1[0];
#pragma unroll
        for (int i = 1; i < 10; ++i) r = (g == i) ? L1[i] : r;
        if (g < K_PP) out[(size_t)b * C_CH + K_C + p * K_PP + g] = r;
    } else {
        // ---- center path: one wave per batch, top-22 of pixel (3,3) ----
        const int c = (blockIdx.x - MAIN_BLOCKS) * 4 + wid;  // batch 0..1023
        const float* src = in + ((size_t)c * NPIX + CENTER_PIX) * C_CH;
        const float4 a0 = *reinterpret_cast<const float4*>(src + lane * 4);
        const float4 a1 = *reinterpret_cast<const float4*>(src + 256 + lane * 4);
        float v[8] = {a0.x, a0.y, a0.z, a0.w, a1.x, a1.y, a1.z, a1.w};
        sort8_desc(v);
        float res = 0.0f;
#pragma unroll
        for (int it = 0; it < K_C; ++it) round1(v, res, lane, it);
        if (lane < K_C) out[(size_t)c * C_CH + lane] = res;
    }
}

extern "C" void kernel_launch(void* const* d_in, const int* in_sizes, int n_in,
                              void* d_out, int out_size, void* d_ws, size_t ws_size,
                              hipStream_t stream) {
    const float* in = (const float*)d_in[0];
    float* out = (float*)d_out;
    channel_topk_kernel<<<MAIN_BLOCKS + CENTER_BLOCKS, 256, 0, stream>>>(in, out);
}

// Round 5
// 23.518 us; speedup vs baseline: 1.6227x; 1.0813x over previous
//
#include <hip/hip_runtime.h>
#include <math.h>

// inputs [B=1024, 7, 7, C=512] f32 NHWC; out [B, 512]:
//   out[b][0:22]          = top-22 of center pixel (3,3)  (k_c = 512%49)
//   out[b][22 + p*10 + j] = top-10 of pixel p             (k_pp = 512//49)
#define NPIX 49
#define C_CH 512
#define CENTER_PIX 24
#define K_PP 10
#define K_C 22
#define CENTER_BLOCKS 256   // FIRST: long-serial-latency waves start at t=0
#define MAIN_BLOCKS 3136    // x4 waves x4 pixels = 50176 pixels

__device__ __forceinline__ float ibc(int x) { return __int_as_float(x); }
__device__ __forceinline__ int fbc(float x) { return __float_as_int(x); }

// Descending compare-exchange.
__device__ __forceinline__ void ce(float& a, float& b) {
    const float mx = fmaxf(a, b), mn = fminf(a, b);
    a = mx; b = mn;
}

// Sort 8 descending — Batcher odd-even mergesort, 19 CE. (Proven R1-R4.)
__device__ __forceinline__ void sort8_desc(float* v) {
    ce(v[0],v[1]); ce(v[2],v[3]); ce(v[4],v[5]); ce(v[6],v[7]);
    ce(v[0],v[2]); ce(v[1],v[3]); ce(v[4],v[6]); ce(v[5],v[7]);
    ce(v[1],v[2]); ce(v[5],v[6]);
    ce(v[0],v[4]); ce(v[1],v[5]); ce(v[2],v[6]); ce(v[3],v[7]);
    ce(v[2],v[4]); ce(v[3],v[5]);
    ce(v[1],v[2]); ce(v[3],v[4]); ce(v[5],v[6]);
}

// Clean a cyclic-bitonic 10-seq to descending order. (Proven R4.)
__device__ __forceinline__ void bitonic10_clean(float (&c)[10]) {
    ce(c[0],c[8]); ce(c[1],c[9]);
    ce(c[2],c[6]); ce(c[3],c[7]); ce(c[4],c[8]); ce(c[5],c[9]);
    ce(c[2],c[4]); ce(c[3],c[5]); ce(c[6],c[8]); ce(c[7],c[9]);
    ce(c[0],c[1]); ce(c[2],c[3]); ce(c[4],c[5]); ce(c[6],c[7]); ce(c[8],c[9]);
}

// Merge two descending sorted-8 lists -> descending sorted top-10. (Proven R4.)
__device__ __forceinline__ void merge88_top10(const float* a, const float* b,
                                              float (&L)[10]) {
    float h[8], l[8];
#pragma unroll
    for (int i = 0; i < 8; ++i) {
        h[i] = fmaxf(a[i], b[7 - i]);   // top-8 (cyclic bitonic)
        l[i] = fminf(a[i], b[7 - i]);   // ranks 9..16 (cyclic bitonic)
    }
    ce(h[0],h[4]); ce(h[1],h[5]); ce(h[2],h[6]); ce(h[3],h[7]);
    ce(h[0],h[2]); ce(h[1],h[3]); ce(h[4],h[6]); ce(h[5],h[7]);
    ce(h[0],h[1]); ce(h[2],h[3]); ce(h[4],h[5]); ce(h[6],h[7]);
    const float m0 = fmaxf(l[0], l[4]), m1 = fmaxf(l[1], l[5]);
    const float m2 = fmaxf(l[2], l[6]), m3 = fmaxf(l[3], l[7]);
    const float n0 = fmaxf(m0, m2), n1 = fmaxf(m1, m3);
#pragma unroll
    for (int i = 0; i < 8; ++i) L[i] = h[i];
    L[8] = fmaxf(n0, n1);
    L[9] = fminf(n0, n1);
}

// a = top-10 of (sorted-10 a ∪ sorted-8 b). Same padded-bitonic wiring as
// R4's merge10_into with b[8]=b[9]=-inf dropped: c[0]=a[0], c[1]=a[1].
__device__ __forceinline__ void merge8_into10(float (&a)[10], const float (&b)[8]) {
    float c[10];
    c[0] = a[0]; c[1] = a[1];
#pragma unroll
    for (int i = 2; i < 10; ++i) c[i] = fmaxf(a[i], b[9 - i]);
    bitonic10_clean(c);
#pragma unroll
    for (int i = 0; i < 10; ++i) a[i] = c[i];
}

// Cross-lane tree level: merge own sorted-10 with row-rotated partner's.
template <int CTRL>
__device__ __forceinline__ void tree_level(float (&T)[10]) {
    float c[10];
#pragma unroll
    for (int i = 0; i < 10; ++i) {
        const int s = fbc(T[9 - i]);
        const int p = __builtin_amdgcn_update_dpp(s, s, CTRL, 0xF, 0xF, false);
        c[i] = fmaxf(T[i], ibc(p));
    }
    bitonic10_clean(c);
#pragma unroll
    for (int i = 0; i < 10; ++i) T[i] = c[i];
}

// ---- center-pixel path (R2-proven serial extraction, 1024 waves only) ----
template <int CTRL>
__device__ __forceinline__ float dpp_maxf(float x) {
    const int xi = fbc(x);
    const int yi = __builtin_amdgcn_update_dpp(xi, xi, CTRL, 0xF, 0xF, false);
    return fmaxf(x, ibc(yi));
}

__device__ __forceinline__ float wave_max_uniform(float x) {
    x = dpp_maxf<0x111>(x);  // row_shr:1
    x = dpp_maxf<0x112>(x);  // row_shr:2
    x = dpp_maxf<0x114>(x);  // row_shr:4
    x = dpp_maxf<0x118>(x);  // row_shr:8
    x = dpp_maxf<0x142>(x);  // row_bcast15
    x = dpp_maxf<0x143>(x);  // row_bcast31
    return ibc(__builtin_amdgcn_readlane(fbc(x), 63));
}

__device__ __forceinline__ void round1(float (&v)[8], float& res, int lane, int it) {
    const float m = wave_max_uniform(v[0]);
    const unsigned long long msk = __ballot(v[0] == m);
    const int owner = __ffsll(msk) - 1;
    const bool own = (lane == owner);
    v[0] = own ? v[1] : v[0];
    v[1] = own ? v[2] : v[1];
    v[2] = own ? v[3] : v[2];
    v[3] = own ? v[4] : v[3];
    v[4] = own ? v[5] : v[4];
    v[5] = own ? v[6] : v[5];
    v[6] = own ? v[7] : v[6];
    v[7] = own ? -INFINITY : v[7];
    res = (lane == it) ? m : res;
}

// min-waves-per-EU = 8 forces VGPR <= 64 -> 8 waves/SIMD residency.
__global__ __launch_bounds__(256, 8) void
channel_topk_kernel(const float* __restrict__ in, float* __restrict__ out) {
    const int wid = threadIdx.x >> 6;
    const int lane = threadIdx.x & 63;

    if (blockIdx.x >= CENTER_BLOCKS) {
        // ---- main path: 16 lanes per pixel, 4 pixels per wave ----
        const int g = lane & 15;
        const int pix = ((blockIdx.x - CENTER_BLOCKS) * 4 + wid) * 4 + (lane >> 4);
        const float* src = in + (size_t)pix * C_CH + g * 4;

        // Lane g owns channels {g*4 + j*64 + k}. Issue all 8 loads up front
        // (max memory-level parallelism); full unroll -> static indexing.
        float4 t[8];
#pragma unroll
        for (int j = 0; j < 8; ++j)
            t[j] = *reinterpret_cast<const float4*>(src + j * 64);

        // Streaming merge: (8,8)->10, then two (10,8)->10. Keeps the live
        // set ~55 VGPRs so the launch-bounds cap doesn't spill.
        float a[8] = {t[0].x, t[0].y, t[0].z, t[0].w, t[1].x, t[1].y, t[1].z, t[1].w};
        float b[8] = {t[2].x, t[2].y, t[2].z, t[2].w, t[3].x, t[3].y, t[3].z, t[3].w};
        sort8_desc(a);
        sort8_desc(b);
        float L[10];
        merge88_top10(a, b, L);

        float s[8] = {t[4].x, t[4].y, t[4].z, t[4].w, t[5].x, t[5].y, t[5].z, t[5].w};
        sort8_desc(s);
        merge8_into10(L, s);

        float s2[8] = {t[6].x, t[6].y, t[6].z, t[6].w, t[7].x, t[7].y, t[7].z, t[7].w};
        sort8_desc(s2);
        merge8_into10(L, s2);

        // rotate-merge across the 16-lane row: exact binary coverage.
        tree_level<0x121>(L);  // row_ror:1
        tree_level<0x122>(L);  // row_ror:2
        tree_level<0x124>(L);  // row_ror:4
        tree_level<0x128>(L);  // row_ror:8

        const int bb = pix / NPIX;
        const int p = pix - bb * NPIX;
        float r = L[0];
#pragma unroll
        for (int i = 1; i < 10; ++i) r = (g == i) ? L[i] : r;
        if (g < K_PP) out[(size_t)bb * C_CH + K_C + p * K_PP + g] = r;
    } else {
        // ---- center path: one wave per batch, top-22 of pixel (3,3) ----
        const int c = blockIdx.x * 4 + wid;  // batch 0..1023
        const float* src = in + ((size_t)c * NPIX + CENTER_PIX) * C_CH;
        const float4 a0 = *reinterpret_cast<const float4*>(src + lane * 4);
        const float4 a1 = *reinterpret_cast<const float4*>(src + 256 + lane * 4);
        float v[8] = {a0.x, a0.y, a0.z, a0.w, a1.x, a1.y, a1.z, a1.w};
        sort8_desc(v);
        float res = 0.0f;
#pragma unroll
        for (int it = 0; it < K_C; ++it) round1(v, res, lane, it);
        if (lane < K_C) out[(size_t)c * C_CH + lane] = res;
    }
}

extern "C" void kernel_launch(void* const* d_in, const int* in_sizes, int n_in,
                              void* d_out, int out_size, void* d_ws, size_t ws_size,
                              hipStream_t stream) {
    const float* in = (const float*)d_in[0];
    float* out = (float*)d_out;
    channel_topk_kernel<<<CENTER_BLOCKS + MAIN_BLOCKS, 256, 0, stream>>>(in, out);
}